// Round 7
// baseline (93.603 us; speedup 1.0000x reference)
//
#include <hip/hip_runtime.h>
#include <math.h>

#define NN 4096
#define FF 128
#define DD 64
#define HH 4
#define NC 256  // HH*DD output columns

typedef _Float16 f16x8 __attribute__((ext_vector_type(8)));
typedef _Float16 f16x2 __attribute__((ext_vector_type(2)));
typedef float    f32x4 __attribute__((ext_vector_type(4)));

// ---------------------------------------------------------------------------
// Kernel 1 (fused): blocks 0..511 = prep (tile = bx>>2, head = bx&3);
// blocks 512..4607 = adjbits row (bx-512). Fusion overlaps the 64MB adj
// read with the projection GEMM instead of serializing two dispatches.
// prep emits Bpack (f16 MFMA-B-fragment-ordered 64dx32m chunks,
// Bpack[h][chunk][cb][lane][8], 4KB contiguous) + f16 exp tables.
// ---------------------------------------------------------------------------
__global__ __launch_bounds__(256) void prep_adj_kernel(
    const int* __restrict__ adj, const float* __restrict__ feats,
    const float* __restrict__ W, const float* __restrict__ ak,
    unsigned int* __restrict__ adjw, _Float16* __restrict__ Bpack,
    _Float16* __restrict__ Es, _Float16* __restrict__ Fs,
    _Float16* __restrict__ En, _Float16* __restrict__ Fn)
{
    const int t = threadIdx.x;

    if (blockIdx.x >= 512) {
        // ---------------- adjbits ----------------
        const int row  = blockIdx.x - 512;
        const int wv   = t >> 6;
        const int lane = t & 63;
        for (int c = wv; c < 64; c += 4) {
            int a = adj[(size_t)row * NN + c * 64 + lane];
            unsigned long long m = __ballot(a != 0);
            if (lane == 0) {
                adjw[row * 128 + c * 2]     = (unsigned int)m;
                adjw[row * 128 + c * 2 + 1] = (unsigned int)(m >> 32);
            }
        }
        return;
    }

    // ---------------- prep ----------------
    __shared__ float Wt[64 * 132];
    __shared__ float ft[32 * 128];
    __shared__ float hlds[32 * 65];
    const int h  = blockIdx.x & 3;
    const int tile = blockIdx.x >> 2;
    const int n0 = tile * 32;

    {
        const float* Wh = W + h * (FF * DD);
        #pragma unroll
        for (int j = 0; j < 8; ++j) {
            int idx = j * 256 + t;
            int f   = idx >> 4;
            int d4  = idx & 15;
            float4 v = ((const float4*)Wh)[idx];
            Wt[(d4 * 4 + 0) * 132 + f] = v.x;
            Wt[(d4 * 4 + 1) * 132 + f] = v.y;
            Wt[(d4 * 4 + 2) * 132 + f] = v.z;
            Wt[(d4 * 4 + 3) * 132 + f] = v.w;
        }
        #pragma unroll
        for (int j = 0; j < 4; ++j) {
            int idx = j * 256 + t;
            int r = idx >> 5, f4 = idx & 31;
            ((float4*)ft)[r * 32 + f4] = ((const float4*)feats)[(size_t)(n0 + r) * 32 + f4];
        }
    }
    __syncthreads();

    const int d   = t & 63;
    const int wid = t >> 6;
    float acc[8];
    #pragma unroll
    for (int j = 0; j < 8; ++j) acc[j] = 0.f;

    for (int f4 = 0; f4 < 32; ++f4) {
        const float4 w4 = *(const float4*)&Wt[d * 132 + f4 * 4];
        #pragma unroll
        for (int j = 0; j < 8; ++j) {
            const int r = wid + 4 * j;
            const float4 fv = *(const float4*)&ft[r * 128 + f4 * 4];
            acc[j] += fv.x * w4.x + fv.y * w4.y + fv.z * w4.z + fv.w * w4.w;
        }
    }

    const float aks = ak[h * 128 + d];
    const float akn = ak[h * 128 + 64 + d];
    #pragma unroll
    for (int j = 0; j < 8; ++j) {
        const int r = wid + 4 * j;
        const float hv = acc[j];
        hlds[r * 65 + d] = hv;
        float v1 = hv * aks;
        float v2 = hv * akn;
        #pragma unroll
        for (int m = 32; m >= 1; m >>= 1) {
            v1 += __shfl_xor(v1, m, 64);
            v2 += __shfl_xor(v2, m, 64);
        }
        if (d == 0) {
            Es[h * NN + n0 + r] = (_Float16)__expf(v1);
            Fs[h * NN + n0 + r] = (_Float16)__expf(0.2f * v1);
            En[h * NN + n0 + r] = (_Float16)__expf(v2);
            Fn[h * NN + n0 + r] = (_Float16)__expf(0.2f * v2);
        }
    }
    __syncthreads();

    // Bpack: thread t = (cb = t>>6, lane l = t&63); element j is
    // H[cb*16 + (l&15)][m0 + (l>>4)*8 + j] = hlds[(l>>4)*8+j][cb*16+(l&15)]
    const int cb = t >> 6;
    const int l  = t & 63;
    const int lr = l & 15;
    const int kg = l >> 4;
    f16x8 v;
    #pragma unroll
    for (int j = 0; j < 8; ++j)
        v[j] = (_Float16)hlds[(kg * 8 + j) * 65 + cb * 16 + lr];
    *(f16x8*)(Bpack + ((size_t)(h * 128 + tile)) * 2048 + (cb * 64 + l) * 8) = v;
}

// ---------------------------------------------------------------------------
// Kernel 2: MFMA attention. Block = 4 waves (one head, 128 rows; wave w owns
// rows bx*128 + w*32 ..+32). Chunk-order ROTATED per block (cq_phys =
// (cq + bx) mod ncq) to decorrelate same-address L2 traffic across blocks.
// Dense Bpack chunk (4KB) staged to LDS double-buffer, 1 barrier/chunk,
// B staged 2 chunks ahead, tables prefetched 1 chunk ahead in named regs.
// A = mask ? max(Es*En, Fs*Fn) : 0 (packed f16). mfma_f32_16x16x32_f16;
// C layout col=lane&15, row=(lane>>4)*4+reg [verified].
// ---------------------------------------------------------------------------
__global__ __launch_bounds__(256, 4) void attn_kernel(
    const unsigned int* __restrict__ adjw, const _Float16* __restrict__ Bpack,
    const _Float16* __restrict__ Es, const _Float16* __restrict__ Fs,
    const _Float16* __restrict__ En, const _Float16* __restrict__ Fn,
    float* __restrict__ pacc, float* __restrict__ pden, int ksplit)
{
    __shared__ _Float16 Blds[2][2048];   // 2 x 4KB double buffer

    const int t  = threadIdx.x;
    const int w  = t >> 6;
    const int l  = t & 63;
    const int lr = l & 15;
    const int kg = l >> 4;
    const int h  = blockIdx.y;
    const int s  = blockIdx.z;
    const int n0 = blockIdx.x * 128 + w * 32;

    const int mstart = s * ksplit;
    const int nchunk = ksplit >> 5;
    const int ncq    = nchunk >> 2;
    const int coff   = blockIdx.x & (ncq - 1);
    const int wb     = mstart >> 5;

    // physical chunk index for logical chunk c
#define PC(c) (((((c) >> 2) + coff) & (ncq - 1)) * 4 + ((c) & 3))

    const _Float16 es0 = Es[h * NN + n0 + lr],      fs0 = Fs[h * NN + n0 + lr];
    const _Float16 es1 = Es[h * NN + n0 + 16 + lr], fs1 = Fs[h * NN + n0 + 16 + lr];
    const f16x2 es20 = {es0, es0}, fs20 = {fs0, fs0};
    const f16x2 es21 = {es1, es1}, fs21 = {fs1, fs1};

    const _Float16* __restrict__ EnB = En + (size_t)h * NN;
    const _Float16* __restrict__ FnB = Fn + (size_t)h * NN;
    const int row0 = n0 + lr, row1 = n0 + 16 + lr;

    // Bpack base for this head+split; chunk stride 2048 f16; thread slice t*8
    const _Float16* __restrict__ bp =
        Bpack + ((size_t)(h * 128) + wb) * 2048 + t * 8;

    f32x4 acc[2][4] = {};
    f32x4 dacc[2]   = {};
    f16x8 ones;
    #pragma unroll
    for (int j = 0; j < 8; ++j) ones[j] = (_Float16)1.0f;

    union U8 { f16x8 v; unsigned int u[4]; };

    // ---- prologue: stage chunk 0, preload chunk 1, tables for chunk 0 ----
    uint4 sreg = *(const uint4*)(bp + (size_t)PC(0) * 2048);
    *(uint4*)&Blds[0][t * 8] = sreg;
    sreg = *(const uint4*)(bp + (size_t)PC(1) * 2048);
    uint4 enqc = *(const uint4*)(EnB + mstart + PC(0) * 32 + kg * 8);
    uint4 fnqc = *(const uint4*)(FnB + mstart + PC(0) * 32 + kg * 8);
    __syncthreads();

    for (int cq = 0; cq < ncq; ++cq) {
        const int cqp = (cq + coff) & (ncq - 1);
        // masks for this cq's 4 physical chunks
        const uint4 mk0 = *(const uint4*)&adjw[(size_t)row0 * 128 + wb + cqp * 4];
        const uint4 mk1 = *(const uint4*)&adjw[(size_t)row1 * 128 + wb + cqp * 4];

        #pragma unroll
        for (int ci = 0; ci < 4; ++ci) {
            const int c = cq * 4 + ci;

            // prefetch B for chunk c+2 (clamped)
            uint4 nreg;
            {
                const int cn = (c + 2 < nchunk) ? c + 2 : c;
                nreg = *(const uint4*)(bp + (size_t)PC(cn) * 2048);
            }
            // stage chunk c+1 into other buffer
            if (c + 1 < nchunk)
                *(uint4*)&Blds[(c + 1) & 1][t * 8] = sreg;
            // prefetch tables for chunk c+1 (clamped)
            uint4 enq_n, fnq_n;
            {
                const int cn = (c + 1 < nchunk) ? c + 1 : c;
                enq_n = *(const uint4*)(EnB + mstart + PC(cn) * 32 + kg * 8);
                fnq_n = *(const uint4*)(FnB + mstart + PC(cn) * 32 + kg * 8);
            }

            // ---- A-frags for chunk c (packed f16) ----
            const unsigned int b0 =
                (ci == 0 ? mk0.x : ci == 1 ? mk0.y : ci == 2 ? mk0.z : mk0.w) >> (kg * 8);
            const unsigned int b1 =
                (ci == 0 ? mk1.x : ci == 1 ? mk1.y : ci == 2 ? mk1.z : mk1.w) >> (kg * 8);
            U8 A0, A1;
            #pragma unroll
            for (int p = 0; p < 4; ++p) {
                const unsigned int eu = p == 0 ? enqc.x : p == 1 ? enqc.y : p == 2 ? enqc.z : enqc.w;
                const unsigned int fu = p == 0 ? fnqc.x : p == 1 ? fnqc.y : p == 2 ? fnqc.z : fnqc.w;
                const f16x2 en2 = __builtin_bit_cast(f16x2, eu);
                const f16x2 fn2 = __builtin_bit_cast(f16x2, fu);
                const f16x2 v0 = __builtin_elementwise_max(es20 * en2, fs20 * fn2);
                const f16x2 v1 = __builtin_elementwise_max(es21 * en2, fs21 * fn2);
                const unsigned int mm0 = (((b0 >> (2 * p)) & 1u) ? 0x0000FFFFu : 0u)
                                       | (((b0 >> (2 * p + 1)) & 1u) ? 0xFFFF0000u : 0u);
                const unsigned int mm1 = (((b1 >> (2 * p)) & 1u) ? 0x0000FFFFu : 0u)
                                       | (((b1 >> (2 * p + 1)) & 1u) ? 0xFFFF0000u : 0u);
                A0.u[p] = __builtin_bit_cast(unsigned int, v0) & mm0;
                A1.u[p] = __builtin_bit_cast(unsigned int, v1) & mm1;
            }

            // ---- B-frags from LDS + MFMA ----
            __builtin_amdgcn_s_setprio(1);
            #pragma unroll
            for (int cb = 0; cb < 4; ++cb) {
                const f16x8 Bf = *(const f16x8*)&Blds[c & 1][(cb * 64 + l) * 8];
                acc[0][cb] = __builtin_amdgcn_mfma_f32_16x16x32_f16(A0.v, Bf, acc[0][cb], 0, 0, 0);
                acc[1][cb] = __builtin_amdgcn_mfma_f32_16x16x32_f16(A1.v, Bf, acc[1][cb], 0, 0, 0);
            }
            dacc[0] = __builtin_amdgcn_mfma_f32_16x16x32_f16(A0.v, ones, dacc[0], 0, 0, 0);
            dacc[1] = __builtin_amdgcn_mfma_f32_16x16x32_f16(A1.v, ones, dacc[1], 0, 0, 0);
            __builtin_amdgcn_s_setprio(0);

            __syncthreads();   // staged chunk c+1 visible; buffer c&1 free
            sreg = nreg;
            enqc = enq_n;
            fnqc = fnq_n;
        }
    }
#undef PC

    #pragma unroll
    for (int rb = 0; rb < 2; ++rb) {
        #pragma unroll
        for (int r = 0; r < 4; ++r) {
            const int row = n0 + rb * 16 + kg * 4 + r;
            #pragma unroll
            for (int cb = 0; cb < 4; ++cb)
                __builtin_nontemporal_store(acc[rb][cb][r],
                    &pacc[((size_t)(s * NN + row)) * NC + h * 64 + cb * 16 + lr]);
            if (lr == 0)
                pden[(s * NN + row) * 4 + h] = dacc[rb][r];
        }
    }
}

// ---------------------------------------------------------------------------
// Kernel 3: reduce splits, normalize, ReLU.
// ---------------------------------------------------------------------------
__global__ __launch_bounds__(256) void finalize_kernel(
    const float* __restrict__ pacc, const float* __restrict__ pden,
    float* __restrict__ out, int nsplit)
{
    const int n = blockIdx.x;
    const int c = threadIdx.x;
    float a = 0.f, d = 0.f;
    for (int s = 0; s < nsplit; ++s) {
        a += pacc[((size_t)(s * NN + n)) * NC + c];
        d += pden[(s * NN + n) * 4 + (c >> 6)];
    }
    const float o = (d > 0.f) ? a / d : 0.f;
    out[(size_t)n * NC + c] = o > 0.f ? o : 0.f;
}

// ---------------------------------------------------------------------------
extern "C" void kernel_launch(void* const* d_in, const int* in_sizes, int n_in,
                              void* d_out, int out_size, void* d_ws, size_t ws_size,
                              hipStream_t stream)
{
    const int*   adj   = (const int*)d_in[0];
    const float* feats = (const float*)d_in[1];
    const float* W     = (const float*)d_in[2];
    const float* ak    = (const float*)d_in[3];
    float*       out   = (float*)d_out;

    char* ws = (char*)d_ws;
    unsigned int* adjw  = (unsigned int*)ws;                          // 2 MB
    _Float16*     Bpack = (_Float16*)(ws + (2ull << 20));             // 2 MB
    _Float16*     Es    = (_Float16*)(ws + (4ull << 20));             // 32 KB
    _Float16*     Fs    = (_Float16*)(ws + (4ull << 20) + (1 << 16)); // 32 KB
    _Float16*     En    = (_Float16*)(ws + (4ull << 20) + (2 << 16)); // 32 KB
    _Float16*     Fn    = (_Float16*)(ws + (4ull << 20) + (3 << 16)); // 32 KB
    float*        pden  = (float*)(ws + (4ull << 20) + (4 << 16));    // <=512 KB
    float*        pacc  = (float*)(ws + (5ull << 20));                // nsplit*4 MB

    int nsplit = 8;
    while (nsplit > 1 && ws_size < (5ull << 20) + (size_t)nsplit * (4ull << 20))
        nsplit >>= 1;
    const int ksplit = NN / nsplit;

    prep_adj_kernel<<<512 + NN, 256, 0, stream>>>(adj, feats, W, ak, adjw,
                                                  Bpack, Es, Fs, En, Fn);
    attn_kernel<<<dim3(32, 4, nsplit), 256, 0, stream>>>(adjw, Bpack, Es, Fs, En, Fn,
                                                         pacc, pden, ksplit);
    finalize_kernel<<<NN, 256, 0, stream>>>(pacc, pden, out, nsplit);
}

// Round 8
// 63.889 us; speedup vs baseline: 1.4651x; 1.4651x over previous
//
#include <hip/hip_runtime.h>
#include <math.h>

#define NN 4096
#define FF 128
#define DD 64
#define HH 4
#define NC 256  // HH*DD output columns

typedef _Float16 f16x8 __attribute__((ext_vector_type(8)));
typedef _Float16 f16x2 __attribute__((ext_vector_type(2)));
typedef float    f32x4 __attribute__((ext_vector_type(4)));

// ---------------------------------------------------------------------------
// Kernel 0: adjacency int32 -> bitmask. Zero LDS -> full occupancy ->
// HBM-rate streaming read of the 64MB adj.
// ---------------------------------------------------------------------------
__global__ __launch_bounds__(256) void adjbits_kernel(
    const int* __restrict__ adj, unsigned int* __restrict__ adjw)
{
    const int row  = blockIdx.x;
    const int wv   = threadIdx.x >> 6;
    const int lane = threadIdx.x & 63;
    for (int c = wv; c < 64; c += 4) {
        int a = adj[(size_t)row * NN + c * 64 + lane];
        unsigned long long m = __ballot(a != 0);
        if (lane == 0) {
            adjw[row * 128 + c * 2]     = (unsigned int)m;
            adjw[row * 128 + c * 2 + 1] = (unsigned int)(m >> 32);
        }
    }
}

// ---------------------------------------------------------------------------
// Kernel 1: h = features @ W[h]; emit Bpack (f16 MFMA-B-fragment-ordered
// tiles: Bpack[h][chunk][cb][lane][8], 4KB contiguous per 64d x 32m chunk)
// and f16 exp tables Es, Fs, En, Fn ([h][n]).
// ---------------------------------------------------------------------------
__global__ __launch_bounds__(256) void prep_kernel(
    const float* __restrict__ feats, const float* __restrict__ W,
    const float* __restrict__ ak, _Float16* __restrict__ Bpack,
    _Float16* __restrict__ Es, _Float16* __restrict__ Fs,
    _Float16* __restrict__ En, _Float16* __restrict__ Fn)
{
    __shared__ float Wt[64 * 132];
    __shared__ float ft[32 * 128];
    __shared__ float hlds[32 * 65];
    const int t  = threadIdx.x;
    const int h  = blockIdx.y;
    const int n0 = blockIdx.x * 32;

    {
        const float* Wh = W + h * (FF * DD);
        #pragma unroll
        for (int j = 0; j < 8; ++j) {
            int idx = j * 256 + t;
            int f   = idx >> 4;
            int d4  = idx & 15;
            float4 v = ((const float4*)Wh)[idx];
            Wt[(d4 * 4 + 0) * 132 + f] = v.x;
            Wt[(d4 * 4 + 1) * 132 + f] = v.y;
            Wt[(d4 * 4 + 2) * 132 + f] = v.z;
            Wt[(d4 * 4 + 3) * 132 + f] = v.w;
        }
        #pragma unroll
        for (int j = 0; j < 4; ++j) {
            int idx = j * 256 + t;
            int r = idx >> 5, f4 = idx & 31;
            ((float4*)ft)[r * 32 + f4] = ((const float4*)feats)[(size_t)(n0 + r) * 32 + f4];
        }
    }
    __syncthreads();

    const int d   = t & 63;
    const int wid = t >> 6;
    float acc[8];
    #pragma unroll
    for (int j = 0; j < 8; ++j) acc[j] = 0.f;

    for (int f4 = 0; f4 < 32; ++f4) {
        const float4 w4 = *(const float4*)&Wt[d * 132 + f4 * 4];
        #pragma unroll
        for (int j = 0; j < 8; ++j) {
            const int r = wid + 4 * j;
            const float4 fv = *(const float4*)&ft[r * 128 + f4 * 4];
            acc[j] += fv.x * w4.x + fv.y * w4.y + fv.z * w4.z + fv.w * w4.w;
        }
    }

    const float aks = ak[h * 128 + d];
    const float akn = ak[h * 128 + 64 + d];
    #pragma unroll
    for (int j = 0; j < 8; ++j) {
        const int r = wid + 4 * j;
        const float hv = acc[j];
        hlds[r * 65 + d] = hv;
        float v1 = hv * aks;
        float v2 = hv * akn;
        #pragma unroll
        for (int m = 32; m >= 1; m >>= 1) {
            v1 += __shfl_xor(v1, m, 64);
            v2 += __shfl_xor(v2, m, 64);
        }
        if (d == 0) {
            Es[h * NN + n0 + r] = (_Float16)__expf(v1);
            Fs[h * NN + n0 + r] = (_Float16)__expf(0.2f * v1);
            En[h * NN + n0 + r] = (_Float16)__expf(v2);
            Fn[h * NN + n0 + r] = (_Float16)__expf(0.2f * v2);
        }
    }
    __syncthreads();

    // Bpack: thread t = (cb = t>>6, lane l = t&63); element j is
    // H[cb*16 + (l&15)][m0 + (l>>4)*8 + j] = hlds[(l>>4)*8+j][cb*16+(l&15)]
    const int cb = t >> 6;
    const int l  = t & 63;
    const int lr = l & 15;
    const int kg = l >> 4;
    f16x8 v;
    #pragma unroll
    for (int j = 0; j < 8; ++j)
        v[j] = (_Float16)hlds[(kg * 8 + j) * 65 + cb * 16 + lr];
    *(f16x8*)(Bpack + ((size_t)(h * 128 + blockIdx.x)) * 2048 + (cb * 64 + l) * 8) = v;
}

// ---------------------------------------------------------------------------
// Kernel 2: MFMA attention (R7 form, unchanged). Block = 4 waves (one head,
// 128 rows). Chunk-order ROTATED per block to decorrelate same-address L2
// traffic. Dense Bpack chunk (4KB) staged to LDS double-buffer, 1 barrier
// per chunk, B staged 2 chunks ahead, tables prefetched 1 ahead in regs.
// A = mask ? max(Es*En, Fs*Fn) : 0 (packed f16). mfma_f32_16x16x32_f16;
// C layout col=lane&15, row=(lane>>4)*4+reg [verified].
// ---------------------------------------------------------------------------
__global__ __launch_bounds__(256, 4) void attn_kernel(
    const unsigned int* __restrict__ adjw, const _Float16* __restrict__ Bpack,
    const _Float16* __restrict__ Es, const _Float16* __restrict__ Fs,
    const _Float16* __restrict__ En, const _Float16* __restrict__ Fn,
    float* __restrict__ pacc, float* __restrict__ pden, int ksplit)
{
    __shared__ _Float16 Blds[2][2048];   // 2 x 4KB double buffer

    const int t  = threadIdx.x;
    const int w  = t >> 6;
    const int l  = t & 63;
    const int lr = l & 15;
    const int kg = l >> 4;
    const int h  = blockIdx.y;
    const int s  = blockIdx.z;
    const int n0 = blockIdx.x * 128 + w * 32;

    const int mstart = s * ksplit;
    const int nchunk = ksplit >> 5;
    const int ncq    = nchunk >> 2;
    const int coff   = blockIdx.x & (ncq - 1);
    const int wb     = mstart >> 5;

#define PC(c) (((((c) >> 2) + coff) & (ncq - 1)) * 4 + ((c) & 3))

    const _Float16 es0 = Es[h * NN + n0 + lr],      fs0 = Fs[h * NN + n0 + lr];
    const _Float16 es1 = Es[h * NN + n0 + 16 + lr], fs1 = Fs[h * NN + n0 + 16 + lr];
    const f16x2 es20 = {es0, es0}, fs20 = {fs0, fs0};
    const f16x2 es21 = {es1, es1}, fs21 = {fs1, fs1};

    const _Float16* __restrict__ EnB = En + (size_t)h * NN;
    const _Float16* __restrict__ FnB = Fn + (size_t)h * NN;
    const int row0 = n0 + lr, row1 = n0 + 16 + lr;

    const _Float16* __restrict__ bp =
        Bpack + ((size_t)(h * 128) + wb) * 2048 + t * 8;

    f32x4 acc[2][4] = {};
    f32x4 dacc[2]   = {};
    f16x8 ones;
    #pragma unroll
    for (int j = 0; j < 8; ++j) ones[j] = (_Float16)1.0f;

    union U8 { f16x8 v; unsigned int u[4]; };

    // ---- prologue ----
    uint4 sreg = *(const uint4*)(bp + (size_t)PC(0) * 2048);
    *(uint4*)&Blds[0][t * 8] = sreg;
    sreg = *(const uint4*)(bp + (size_t)PC(1) * 2048);
    uint4 enqc = *(const uint4*)(EnB + mstart + PC(0) * 32 + kg * 8);
    uint4 fnqc = *(const uint4*)(FnB + mstart + PC(0) * 32 + kg * 8);
    __syncthreads();

    for (int cq = 0; cq < ncq; ++cq) {
        const int cqp = (cq + coff) & (ncq - 1);
        const uint4 mk0 = *(const uint4*)&adjw[(size_t)row0 * 128 + wb + cqp * 4];
        const uint4 mk1 = *(const uint4*)&adjw[(size_t)row1 * 128 + wb + cqp * 4];

        #pragma unroll
        for (int ci = 0; ci < 4; ++ci) {
            const int c = cq * 4 + ci;

            uint4 nreg;
            {
                const int cn = (c + 2 < nchunk) ? c + 2 : c;
                nreg = *(const uint4*)(bp + (size_t)PC(cn) * 2048);
            }
            if (c + 1 < nchunk)
                *(uint4*)&Blds[(c + 1) & 1][t * 8] = sreg;
            uint4 enq_n, fnq_n;
            {
                const int cn = (c + 1 < nchunk) ? c + 1 : c;
                enq_n = *(const uint4*)(EnB + mstart + PC(cn) * 32 + kg * 8);
                fnq_n = *(const uint4*)(FnB + mstart + PC(cn) * 32 + kg * 8);
            }

            const unsigned int b0 =
                (ci == 0 ? mk0.x : ci == 1 ? mk0.y : ci == 2 ? mk0.z : mk0.w) >> (kg * 8);
            const unsigned int b1 =
                (ci == 0 ? mk1.x : ci == 1 ? mk1.y : ci == 2 ? mk1.z : mk1.w) >> (kg * 8);
            U8 A0, A1;
            #pragma unroll
            for (int p = 0; p < 4; ++p) {
                const unsigned int eu = p == 0 ? enqc.x : p == 1 ? enqc.y : p == 2 ? enqc.z : enqc.w;
                const unsigned int fu = p == 0 ? fnqc.x : p == 1 ? fnqc.y : p == 2 ? fnqc.z : fnqc.w;
                const f16x2 en2 = __builtin_bit_cast(f16x2, eu);
                const f16x2 fn2 = __builtin_bit_cast(f16x2, fu);
                const f16x2 v0 = __builtin_elementwise_max(es20 * en2, fs20 * fn2);
                const f16x2 v1 = __builtin_elementwise_max(es21 * en2, fs21 * fn2);
                const unsigned int mm0 = (((b0 >> (2 * p)) & 1u) ? 0x0000FFFFu : 0u)
                                       | (((b0 >> (2 * p + 1)) & 1u) ? 0xFFFF0000u : 0u);
                const unsigned int mm1 = (((b1 >> (2 * p)) & 1u) ? 0x0000FFFFu : 0u)
                                       | (((b1 >> (2 * p + 1)) & 1u) ? 0xFFFF0000u : 0u);
                A0.u[p] = __builtin_bit_cast(unsigned int, v0) & mm0;
                A1.u[p] = __builtin_bit_cast(unsigned int, v1) & mm1;
            }

            __builtin_amdgcn_s_setprio(1);
            #pragma unroll
            for (int cb = 0; cb < 4; ++cb) {
                const f16x8 Bf = *(const f16x8*)&Blds[c & 1][(cb * 64 + l) * 8];
                acc[0][cb] = __builtin_amdgcn_mfma_f32_16x16x32_f16(A0.v, Bf, acc[0][cb], 0, 0, 0);
                acc[1][cb] = __builtin_amdgcn_mfma_f32_16x16x32_f16(A1.v, Bf, acc[1][cb], 0, 0, 0);
            }
            dacc[0] = __builtin_amdgcn_mfma_f32_16x16x32_f16(A0.v, ones, dacc[0], 0, 0, 0);
            dacc[1] = __builtin_amdgcn_mfma_f32_16x16x32_f16(A1.v, ones, dacc[1], 0, 0, 0);
            __builtin_amdgcn_s_setprio(0);

            __syncthreads();
            sreg = nreg;
            enqc = enq_n;
            fnqc = fnq_n;
        }
    }
#undef PC

    #pragma unroll
    for (int rb = 0; rb < 2; ++rb) {
        #pragma unroll
        for (int r = 0; r < 4; ++r) {
            const int row = n0 + rb * 16 + kg * 4 + r;
            #pragma unroll
            for (int cb = 0; cb < 4; ++cb)
                __builtin_nontemporal_store(acc[rb][cb][r],
                    &pacc[((size_t)(s * NN + row)) * NC + h * 64 + cb * 16 + lr]);
            if (lr == 0)
                pden[(s * NN + row) * 4 + h] = dacc[rb][r];
        }
    }
}

// ---------------------------------------------------------------------------
// Kernel 3: reduce splits, normalize, ReLU.
// ---------------------------------------------------------------------------
__global__ __launch_bounds__(256) void finalize_kernel(
    const float* __restrict__ pacc, const float* __restrict__ pden,
    float* __restrict__ out, int nsplit)
{
    const int n = blockIdx.x;
    const int c = threadIdx.x;
    float a = 0.f, d = 0.f;
    for (int s = 0; s < nsplit; ++s) {
        a += pacc[((size_t)(s * NN + n)) * NC + c];
        d += pden[(s * NN + n) * 4 + (c >> 6)];
    }
    const float o = (d > 0.f) ? a / d : 0.f;
    out[(size_t)n * NC + c] = o > 0.f ? o : 0.f;
}

// ---------------------------------------------------------------------------
extern "C" void kernel_launch(void* const* d_in, const int* in_sizes, int n_in,
                              void* d_out, int out_size, void* d_ws, size_t ws_size,
                              hipStream_t stream)
{
    const int*   adj   = (const int*)d_in[0];
    const float* feats = (const float*)d_in[1];
    const float* W     = (const float*)d_in[2];
    const float* ak    = (const float*)d_in[3];
    float*       out   = (float*)d_out;

    char* ws = (char*)d_ws;
    unsigned int* adjw  = (unsigned int*)ws;                          // 2 MB
    _Float16*     Bpack = (_Float16*)(ws + (2ull << 20));             // 2 MB
    _Float16*     Es    = (_Float16*)(ws + (4ull << 20));             // 32 KB
    _Float16*     Fs    = (_Float16*)(ws + (4ull << 20) + (1 << 16)); // 32 KB
    _Float16*     En    = (_Float16*)(ws + (4ull << 20) + (2 << 16)); // 32 KB
    _Float16*     Fn    = (_Float16*)(ws + (4ull << 20) + (3 << 16)); // 32 KB
    float*        pden  = (float*)(ws + (4ull << 20) + (4 << 16));    // <=512 KB
    float*        pacc  = (float*)(ws + (5ull << 20));                // nsplit*4 MB

    int nsplit = 8;
    while (nsplit > 1 && ws_size < (5ull << 20) + (size_t)nsplit * (4ull << 20))
        nsplit >>= 1;
    const int ksplit = NN / nsplit;

    adjbits_kernel<<<NN, 256, 0, stream>>>(adj, adjw);
    prep_kernel<<<dim3(128, 4), 256, 0, stream>>>(feats, W, ak, Bpack, Es, Fs, En, Fn);
    attn_kernel<<<dim3(32, 4, nsplit), 256, 0, stream>>>(adjw, Bpack, Es, Fs, En, Fn,
                                                         pacc, pden, ksplit);
    finalize_kernel<<<NN, 256, 0, stream>>>(pacc, pden, out, nsplit);
}

// Round 9
// 55.806 us; speedup vs baseline: 1.6773x; 1.1448x over previous
//
#include <hip/hip_runtime.h>
#include <math.h>

#define NN 4096
#define FF 128
#define DD 64
#define HH 4
#define NC 256  // HH*DD output columns

typedef _Float16 f16x8 __attribute__((ext_vector_type(8)));
typedef _Float16 f16x2 __attribute__((ext_vector_type(2)));
typedef float    f32x4 __attribute__((ext_vector_type(4)));

// ---------------------------------------------------------------------------
// Kernel 0: adjacency int32 -> bitmask, ballot-free. One thread = one 32-bit
// mask word built from its own 32 contiguous ints (8 independent int4 loads,
// per-lane packing, coalesced 4B store). adjw[n*128+w] bit b = adj[n][w*32+b].
// ---------------------------------------------------------------------------
__global__ __launch_bounds__(256) void adjbits_kernel(
    const int* __restrict__ adj, unsigned int* __restrict__ adjw)
{
    const int w = blockIdx.x * 256 + threadIdx.x;   // word index, 524288 total
    const int4* __restrict__ p = (const int4*)(adj + (size_t)w * 32);
    unsigned int m = 0;
    #pragma unroll
    for (int i = 0; i < 8; ++i) {
        const int4 v = p[i];
        m |= (v.x != 0 ? 1u : 0u) << (i * 4);
        m |= (v.y != 0 ? 2u : 0u) << (i * 4);
        m |= (v.z != 0 ? 4u : 0u) << (i * 4);
        m |= (v.w != 0 ? 8u : 0u) << (i * 4);
    }
    adjw[w] = m;
}

// ---------------------------------------------------------------------------
// Kernel 1: h = features @ W[h]; emit Bpack (f16 MFMA-B-fragment-ordered
// tiles: Bpack[h][chunk][cb][lane][8], 4KB contiguous per 64d x 32m chunk)
// and f16 exp tables Es, Fs, En, Fn ([h][n]).
// ---------------------------------------------------------------------------
__global__ __launch_bounds__(256) void prep_kernel(
    const float* __restrict__ feats, const float* __restrict__ W,
    const float* __restrict__ ak, _Float16* __restrict__ Bpack,
    _Float16* __restrict__ Es, _Float16* __restrict__ Fs,
    _Float16* __restrict__ En, _Float16* __restrict__ Fn)
{
    __shared__ float Wt[64 * 132];
    __shared__ float ft[32 * 128];
    __shared__ float hlds[32 * 65];
    const int t  = threadIdx.x;
    const int h  = blockIdx.y;
    const int n0 = blockIdx.x * 32;

    {
        const float* Wh = W + h * (FF * DD);
        #pragma unroll
        for (int j = 0; j < 8; ++j) {
            int idx = j * 256 + t;
            int f   = idx >> 4;
            int d4  = idx & 15;
            float4 v = ((const float4*)Wh)[idx];
            Wt[(d4 * 4 + 0) * 132 + f] = v.x;
            Wt[(d4 * 4 + 1) * 132 + f] = v.y;
            Wt[(d4 * 4 + 2) * 132 + f] = v.z;
            Wt[(d4 * 4 + 3) * 132 + f] = v.w;
        }
        #pragma unroll
        for (int j = 0; j < 4; ++j) {
            int idx = j * 256 + t;
            int r = idx >> 5, f4 = idx & 31;
            ((float4*)ft)[r * 32 + f4] = ((const float4*)feats)[(size_t)(n0 + r) * 32 + f4];
        }
    }
    __syncthreads();

    const int d   = t & 63;
    const int wid = t >> 6;
    float acc[8];
    #pragma unroll
    for (int j = 0; j < 8; ++j) acc[j] = 0.f;

    for (int f4 = 0; f4 < 32; ++f4) {
        const float4 w4 = *(const float4*)&Wt[d * 132 + f4 * 4];
        #pragma unroll
        for (int j = 0; j < 8; ++j) {
            const int r = wid + 4 * j;
            const float4 fv = *(const float4*)&ft[r * 128 + f4 * 4];
            acc[j] += fv.x * w4.x + fv.y * w4.y + fv.z * w4.z + fv.w * w4.w;
        }
    }

    const float aks = ak[h * 128 + d];
    const float akn = ak[h * 128 + 64 + d];
    #pragma unroll
    for (int j = 0; j < 8; ++j) {
        const int r = wid + 4 * j;
        const float hv = acc[j];
        hlds[r * 65 + d] = hv;
        float v1 = hv * aks;
        float v2 = hv * akn;
        #pragma unroll
        for (int m = 32; m >= 1; m >>= 1) {
            v1 += __shfl_xor(v1, m, 64);
            v2 += __shfl_xor(v2, m, 64);
        }
        if (d == 0) {
            Es[h * NN + n0 + r] = (_Float16)__expf(v1);
            Fs[h * NN + n0 + r] = (_Float16)__expf(0.2f * v1);
            En[h * NN + n0 + r] = (_Float16)__expf(v2);
            Fn[h * NN + n0 + r] = (_Float16)__expf(0.2f * v2);
        }
    }
    __syncthreads();

    const int cb = t >> 6;
    const int l  = t & 63;
    const int lr = l & 15;
    const int kg = l >> 4;
    f16x8 v;
    #pragma unroll
    for (int j = 0; j < 8; ++j)
        v[j] = (_Float16)hlds[(kg * 8 + j) * 65 + cb * 16 + lr];
    *(f16x8*)(Bpack + ((size_t)(h * 128 + blockIdx.x)) * 2048 + (cb * 64 + l) * 8) = v;
}

// ---------------------------------------------------------------------------
// Kernel 2: MFMA attention (R7 form; nontemporal stores dropped so pacc
// stays L2/L3-resident for finalize). Block = 4 waves (one head, 128 rows).
// Chunk-order ROTATED per block; dense Bpack chunk staged to LDS double
// buffer, 1 barrier/chunk, B staged 2 chunks ahead, tables 1 ahead in regs.
// A = mask ? max(Es*En, Fs*Fn) : 0 (packed f16). mfma_f32_16x16x32_f16.
// ---------------------------------------------------------------------------
__global__ __launch_bounds__(256, 4) void attn_kernel(
    const unsigned int* __restrict__ adjw, const _Float16* __restrict__ Bpack,
    const _Float16* __restrict__ Es, const _Float16* __restrict__ Fs,
    const _Float16* __restrict__ En, const _Float16* __restrict__ Fn,
    float* __restrict__ pacc, float* __restrict__ pden, int ksplit)
{
    __shared__ _Float16 Blds[2][2048];   // 2 x 4KB double buffer

    const int t  = threadIdx.x;
    const int w  = t >> 6;
    const int l  = t & 63;
    const int lr = l & 15;
    const int kg = l >> 4;
    const int h  = blockIdx.y;
    const int s  = blockIdx.z;
    const int n0 = blockIdx.x * 128 + w * 32;

    const int mstart = s * ksplit;
    const int nchunk = ksplit >> 5;
    const int ncq    = nchunk >> 2;
    const int coff   = blockIdx.x & (ncq - 1);
    const int wb     = mstart >> 5;

#define PC(c) (((((c) >> 2) + coff) & (ncq - 1)) * 4 + ((c) & 3))

    const _Float16 es0 = Es[h * NN + n0 + lr],      fs0 = Fs[h * NN + n0 + lr];
    const _Float16 es1 = Es[h * NN + n0 + 16 + lr], fs1 = Fs[h * NN + n0 + 16 + lr];
    const f16x2 es20 = {es0, es0}, fs20 = {fs0, fs0};
    const f16x2 es21 = {es1, es1}, fs21 = {fs1, fs1};

    const _Float16* __restrict__ EnB = En + (size_t)h * NN;
    const _Float16* __restrict__ FnB = Fn + (size_t)h * NN;
    const int row0 = n0 + lr, row1 = n0 + 16 + lr;

    const _Float16* __restrict__ bp =
        Bpack + ((size_t)(h * 128) + wb) * 2048 + t * 8;

    f32x4 acc[2][4] = {};
    f32x4 dacc[2]   = {};
    f16x8 ones;
    #pragma unroll
    for (int j = 0; j < 8; ++j) ones[j] = (_Float16)1.0f;

    union U8 { f16x8 v; unsigned int u[4]; };

    // ---- prologue ----
    uint4 sreg = *(const uint4*)(bp + (size_t)PC(0) * 2048);
    *(uint4*)&Blds[0][t * 8] = sreg;
    sreg = *(const uint4*)(bp + (size_t)PC(1) * 2048);
    uint4 enqc = *(const uint4*)(EnB + mstart + PC(0) * 32 + kg * 8);
    uint4 fnqc = *(const uint4*)(FnB + mstart + PC(0) * 32 + kg * 8);
    __syncthreads();

    for (int cq = 0; cq < ncq; ++cq) {
        const int cqp = (cq + coff) & (ncq - 1);
        const uint4 mk0 = *(const uint4*)&adjw[(size_t)row0 * 128 + wb + cqp * 4];
        const uint4 mk1 = *(const uint4*)&adjw[(size_t)row1 * 128 + wb + cqp * 4];

        #pragma unroll
        for (int ci = 0; ci < 4; ++ci) {
            const int c = cq * 4 + ci;

            uint4 nreg;
            {
                const int cn = (c + 2 < nchunk) ? c + 2 : c;
                nreg = *(const uint4*)(bp + (size_t)PC(cn) * 2048);
            }
            if (c + 1 < nchunk)
                *(uint4*)&Blds[(c + 1) & 1][t * 8] = sreg;
            uint4 enq_n, fnq_n;
            {
                const int cn = (c + 1 < nchunk) ? c + 1 : c;
                enq_n = *(const uint4*)(EnB + mstart + PC(cn) * 32 + kg * 8);
                fnq_n = *(const uint4*)(FnB + mstart + PC(cn) * 32 + kg * 8);
            }

            const unsigned int b0 =
                (ci == 0 ? mk0.x : ci == 1 ? mk0.y : ci == 2 ? mk0.z : mk0.w) >> (kg * 8);
            const unsigned int b1 =
                (ci == 0 ? mk1.x : ci == 1 ? mk1.y : ci == 2 ? mk1.z : mk1.w) >> (kg * 8);
            U8 A0, A1;
            #pragma unroll
            for (int p = 0; p < 4; ++p) {
                const unsigned int eu = p == 0 ? enqc.x : p == 1 ? enqc.y : p == 2 ? enqc.z : enqc.w;
                const unsigned int fu = p == 0 ? fnqc.x : p == 1 ? fnqc.y : p == 2 ? fnqc.z : fnqc.w;
                const f16x2 en2 = __builtin_bit_cast(f16x2, eu);
                const f16x2 fn2 = __builtin_bit_cast(f16x2, fu);
                const f16x2 v0 = __builtin_elementwise_max(es20 * en2, fs20 * fn2);
                const f16x2 v1 = __builtin_elementwise_max(es21 * en2, fs21 * fn2);
                const unsigned int mm0 = (((b0 >> (2 * p)) & 1u) ? 0x0000FFFFu : 0u)
                                       | (((b0 >> (2 * p + 1)) & 1u) ? 0xFFFF0000u : 0u);
                const unsigned int mm1 = (((b1 >> (2 * p)) & 1u) ? 0x0000FFFFu : 0u)
                                       | (((b1 >> (2 * p + 1)) & 1u) ? 0xFFFF0000u : 0u);
                A0.u[p] = __builtin_bit_cast(unsigned int, v0) & mm0;
                A1.u[p] = __builtin_bit_cast(unsigned int, v1) & mm1;
            }

            __builtin_amdgcn_s_setprio(1);
            #pragma unroll
            for (int cb = 0; cb < 4; ++cb) {
                const f16x8 Bf = *(const f16x8*)&Blds[c & 1][(cb * 64 + l) * 8];
                acc[0][cb] = __builtin_amdgcn_mfma_f32_16x16x32_f16(A0.v, Bf, acc[0][cb], 0, 0, 0);
                acc[1][cb] = __builtin_amdgcn_mfma_f32_16x16x32_f16(A1.v, Bf, acc[1][cb], 0, 0, 0);
            }
            dacc[0] = __builtin_amdgcn_mfma_f32_16x16x32_f16(A0.v, ones, dacc[0], 0, 0, 0);
            dacc[1] = __builtin_amdgcn_mfma_f32_16x16x32_f16(A1.v, ones, dacc[1], 0, 0, 0);
            __builtin_amdgcn_s_setprio(0);

            __syncthreads();
            sreg = nreg;
            enqc = enq_n;
            fnqc = fnq_n;
        }
    }
#undef PC

    #pragma unroll
    for (int rb = 0; rb < 2; ++rb) {
        #pragma unroll
        for (int r = 0; r < 4; ++r) {
            const int row = n0 + rb * 16 + kg * 4 + r;
            #pragma unroll
            for (int cb = 0; cb < 4; ++cb)
                pacc[((size_t)(s * NN + row)) * NC + h * 64 + cb * 16 + lr] = acc[rb][cb][r];
            if (lr == 0)
                pden[(s * NN + row) * 4 + h] = dacc[rb][r];
        }
    }
}

// ---------------------------------------------------------------------------
// Kernel 3: reduce splits, normalize, ReLU. float4 per thread, 4 rows/block.
// ---------------------------------------------------------------------------
__global__ __launch_bounds__(256) void finalize_kernel(
    const float* __restrict__ pacc, const float* __restrict__ pden,
    float* __restrict__ out, int nsplit)
{
    const int t = threadIdx.x;
    const int n = blockIdx.x * 4 + (t >> 6);
    const int q = t & 63;              // float4 index; cols q*4..q*4+3
    const int h = q >> 4;              // head of these 4 cols

    f32x4 a = {0.f, 0.f, 0.f, 0.f};
    float d = 0.f;
    for (int s = 0; s < nsplit; ++s) {
        a += *(const f32x4*)&pacc[((size_t)(s * NN + n)) * NC + q * 4];
        d += pden[(s * NN + n) * 4 + h];
    }
    f32x4 o;
    const float inv = (d > 0.f) ? 1.0f / d : 0.f;
    #pragma unroll
    for (int i = 0; i < 4; ++i) {
        const float v = a[i] * inv;
        o[i] = v > 0.f ? v : 0.f;
    }
    *(f32x4*)&out[(size_t)n * NC + q * 4] = o;
}

// ---------------------------------------------------------------------------
extern "C" void kernel_launch(void* const* d_in, const int* in_sizes, int n_in,
                              void* d_out, int out_size, void* d_ws, size_t ws_size,
                              hipStream_t stream)
{
    const int*   adj   = (const int*)d_in[0];
    const float* feats = (const float*)d_in[1];
    const float* W     = (const float*)d_in[2];
    const float* ak    = (const float*)d_in[3];
    float*       out   = (float*)d_out;

    char* ws = (char*)d_ws;
    unsigned int* adjw  = (unsigned int*)ws;                          // 2 MB
    _Float16*     Bpack = (_Float16*)(ws + (2ull << 20));             // 2 MB
    _Float16*     Es    = (_Float16*)(ws + (4ull << 20));             // 32 KB
    _Float16*     Fs    = (_Float16*)(ws + (4ull << 20) + (1 << 16)); // 32 KB
    _Float16*     En    = (_Float16*)(ws + (4ull << 20) + (2 << 16)); // 32 KB
    _Float16*     Fn    = (_Float16*)(ws + (4ull << 20) + (3 << 16)); // 32 KB
    float*        pden  = (float*)(ws + (4ull << 20) + (4 << 16));    // <=512 KB
    float*        pacc  = (float*)(ws + (5ull << 20));                // nsplit*4 MB

    int nsplit = 8;
    while (nsplit > 1 && ws_size < (5ull << 20) + (size_t)nsplit * (4ull << 20))
        nsplit >>= 1;
    const int ksplit = NN / nsplit;

    adjbits_kernel<<<2048, 256, 0, stream>>>(adj, adjw);
    prep_kernel<<<dim3(128, 4), 256, 0, stream>>>(feats, W, ak, Bpack, Es, Fs, En, Fn);
    attn_kernel<<<dim3(32, 4, nsplit), 256, 0, stream>>>(adjw, Bpack, Es, Fs, En, Fn,
                                                         pacc, pden, ksplit);
    finalize_kernel<<<1024, 256, 0, stream>>>(pacc, pden, out, nsplit);
}